// Round 3
// baseline (425.862 us; speedup 1.0000x reference)
//
#include <hip/hip_runtime.h>
#include <stdint.h>
#include <math.h>

// GAT layer, restructured:
//   dst-term and b_attn cancel in softmax over j; masked exp()==0 exactly.
//   p_j = exp(src_j) (no max needed: |src|<~0.7), G = [p*hsum | p] in fp16,
//   out = (adj @ G_num) / (adj @ p) / n via f16 MFMA, adj converted on the fly.
// R3: split-K (x4) on the adj@G GEMM -> 1024 blocks (16 waves/CU) to hide
//     HBM latency; fp32 partials in ws + finalize kernel.

#define Bz   4
#define Nn   4096
#define Dd   256
#define OUTd 64
#define GTR  80   // 64 hsum rows + 1 p row + 15 pad rows (poison; cols 65..79 ignored)
#define KSPLIT 4
#define KCH  (Nn / KSPLIT)

typedef float    f32x4   __attribute__((ext_vector_type(4)));
typedef __fp16   fp16x2  __attribute__((ext_vector_type(2)));   // cvt_pkrtz return type
typedef _Float16 half8_t __attribute__((ext_vector_type(8)));

__device__ inline half8_t cvt8(float4 a, float4 b) {
  union { fp16x2 h2[4]; half8_t h8; } r;
  r.h2[0] = __builtin_amdgcn_cvt_pkrtz(a.x, a.y);
  r.h2[1] = __builtin_amdgcn_cvt_pkrtz(a.z, a.w);
  r.h2[2] = __builtin_amdgcn_cvt_pkrtz(b.x, b.y);
  r.h2[3] = __builtin_amdgcn_cvt_pkrtz(b.z, b.w);
  return r.h8;
}

// ---- prep: w_s[ho] = mean_k Wa[k,h,l] (src half), hb[l] = sum_h b_fc, sb = b_fc . w_s
__global__ __launch_bounds__(256) void k_prep_ws(const float* __restrict__ W_attn,
                                                 const float* __restrict__ b_fc,
                                                 float* __restrict__ w_s,
                                                 float* __restrict__ hb,
                                                 float* __restrict__ sb) {
  __shared__ float ws_sh[256];
  __shared__ float red[64];
  int t = threadIdx.x;
  int h = t >> 6, l = t & 63;
  float s = 0.f;
  for (int k = 0; k < 4; ++k) s += W_attn[k * 512 + h * 128 + l];
  s *= 0.25f;
  ws_sh[t] = s;
  w_s[t] = s;
  if (t < 64) {
    float hbv = 0.f;
    for (int hh = 0; hh < 4; ++hh) hbv += b_fc[hh * 64 + t];
    hb[t] = hbv;
  }
  __syncthreads();
  if (t < 64) {
    float p = 0.f;
    for (int k = 0; k < 4; ++k) p += b_fc[t + 64 * k] * ws_sh[t + 64 * k];
    red[t] = p;
  }
  __syncthreads();
  if (t == 0) {
    float a = 0.f;
    for (int i = 0; i < 64; ++i) a += red[i];
    *sb = a;
  }
}

// ---- prep: Ut[l][d] fp16.  l<64: sum_h W_fc[h*64+l][d];  l==64: v[d] = sum_ho W_fc[ho][d]*w_s[ho]
__global__ __launch_bounds__(256) void k_prep_ut(const float* __restrict__ W_fc,
                                                 const float* __restrict__ w_s,
                                                 _Float16* __restrict__ Ut) {
  int l = blockIdx.x, d = threadIdx.x;
  float v;
  if (l < 64) {
    v = W_fc[l * 256 + d] + W_fc[(64 + l) * 256 + d] +
        W_fc[(128 + l) * 256 + d] + W_fc[(192 + l) * 256 + d];
  } else {
    v = 0.f;
    for (int ho = 0; ho < 256; ++ho) v += W_fc[ho * 256 + d] * w_s[ho];
  }
  Ut[l * 256 + d] = (_Float16)v;
}

// ---- stage 1: Gt[b][l][j] = fp16(p_j * hsum_lj), Gt[b][64][j] = fp16(p_j)
__global__ __launch_bounds__(256) void k_feat(const float* __restrict__ feat,
                                              const _Float16* __restrict__ Ut,
                                              const float* __restrict__ hb,
                                              const float* __restrict__ sb,
                                              _Float16* __restrict__ Gt) {
  const int b = blockIdx.y;
  const int tid = threadIdx.x;
  const int lane = tid & 63;
  const int wv = tid >> 6;
  const int ln15 = lane & 15;
  const int quad = lane >> 4;
  const int j = blockIdx.x * 64 + wv * 16 + ln15;

  const float* frow = feat + ((size_t)b * Nn + j) * Dd + quad * 8;
  f32x4 acc0 = {0,0,0,0}, acc1 = {0,0,0,0}, acc2 = {0,0,0,0}, acc3 = {0,0,0,0}, acc4 = {0,0,0,0};

  #pragma unroll
  for (int d0 = 0; d0 < Dd; d0 += 32) {
    float4 F0 = *(const float4*)(frow + d0);
    float4 F1 = *(const float4*)(frow + d0 + 4);
    half8_t bf = cvt8(F0, F1);
    const _Float16* up = Ut + (size_t)ln15 * Dd + d0 + quad * 8;
    acc0 = __builtin_amdgcn_mfma_f32_16x16x32_f16(*(const half8_t*)(up + 0 * 16 * Dd), bf, acc0, 0, 0, 0);
    acc1 = __builtin_amdgcn_mfma_f32_16x16x32_f16(*(const half8_t*)(up + 1 * 16 * Dd), bf, acc1, 0, 0, 0);
    acc2 = __builtin_amdgcn_mfma_f32_16x16x32_f16(*(const half8_t*)(up + 2 * 16 * Dd), bf, acc2, 0, 0, 0);
    acc3 = __builtin_amdgcn_mfma_f32_16x16x32_f16(*(const half8_t*)(up + 3 * 16 * Dd), bf, acc3, 0, 0, 0);
    acc4 = __builtin_amdgcn_mfma_f32_16x16x32_f16(*(const half8_t*)(up + 4 * 16 * Dd), bf, acc4, 0, 0, 0);
  }
  float srcv = __shfl(acc4[0], ln15) + sb[0];
  float p = expf(srcv);
  _Float16* gb = Gt + (size_t)b * GTR * Nn;
  #pragma unroll
  for (int r = 0; r < 4; ++r) {
    int lb = quad * 4 + r;
    gb[(size_t)(0  + lb) * Nn + j] = (_Float16)((acc0[r] + hb[0  + lb]) * p);
    gb[(size_t)(16 + lb) * Nn + j] = (_Float16)((acc1[r] + hb[16 + lb]) * p);
    gb[(size_t)(32 + lb) * Nn + j] = (_Float16)((acc2[r] + hb[32 + lb]) * p);
    gb[(size_t)(48 + lb) * Nn + j] = (_Float16)((acc3[r] + hb[48 + lb]) * p);
  }
  if (quad == 0) gb[(size_t)64 * Nn + j] = (_Float16)p;
}

// ---- stage 2 (split-K): part[z][b][i][80] = adj[b][i][kz] @ Gt[b][:][kz]^T  (fp32)
__global__ __launch_bounds__(256) void k_agg(const float* __restrict__ adj,
                                             const _Float16* __restrict__ Gt,
                                             float* __restrict__ part) {
  const int b = blockIdx.y;
  const int z = blockIdx.z;
  const int tid = threadIdx.x;
  const int lane = tid & 63;
  const int wv = tid >> 6;
  const int ln15 = lane & 15;
  const int quad = lane >> 4;
  const int i0 = blockIdx.x * 64 + wv * 16;

  const float* arow = adj + ((size_t)b * Nn + (i0 + ln15)) * (size_t)Nn + quad * 8;
  const _Float16* g0 = Gt + ((size_t)b * GTR + ln15) * Nn + quad * 8;
  const _Float16* g1 = g0 + (size_t)16 * Nn;
  const _Float16* g2 = g0 + (size_t)32 * Nn;
  const _Float16* g3 = g0 + (size_t)48 * Nn;
  const _Float16* g4 = g0 + (size_t)64 * Nn;

  f32x4 acc0 = {0,0,0,0}, acc1 = {0,0,0,0}, acc2 = {0,0,0,0}, acc3 = {0,0,0,0}, acc4 = {0,0,0,0};

  const int kbeg = z * KCH, kend = kbeg + KCH;
  for (int k0 = kbeg; k0 < kend; k0 += 64) {
    float4 A0 = *(const float4*)(arow + k0);
    float4 A1 = *(const float4*)(arow + k0 + 4);
    float4 A2 = *(const float4*)(arow + k0 + 32);
    float4 A3 = *(const float4*)(arow + k0 + 36);
    half8_t b00 = *(const half8_t*)(g0 + k0);
    half8_t b01 = *(const half8_t*)(g1 + k0);
    half8_t b02 = *(const half8_t*)(g2 + k0);
    half8_t b03 = *(const half8_t*)(g3 + k0);
    half8_t b04 = *(const half8_t*)(g4 + k0);
    half8_t b10 = *(const half8_t*)(g0 + k0 + 32);
    half8_t b11 = *(const half8_t*)(g1 + k0 + 32);
    half8_t b12 = *(const half8_t*)(g2 + k0 + 32);
    half8_t b13 = *(const half8_t*)(g3 + k0 + 32);
    half8_t b14 = *(const half8_t*)(g4 + k0 + 32);
    half8_t aF0 = cvt8(A0, A1);   // adj is exactly 0/1 -> exact in fp16
    half8_t aF1 = cvt8(A2, A3);
    acc0 = __builtin_amdgcn_mfma_f32_16x16x32_f16(aF0, b00, acc0, 0, 0, 0);
    acc1 = __builtin_amdgcn_mfma_f32_16x16x32_f16(aF0, b01, acc1, 0, 0, 0);
    acc2 = __builtin_amdgcn_mfma_f32_16x16x32_f16(aF0, b02, acc2, 0, 0, 0);
    acc3 = __builtin_amdgcn_mfma_f32_16x16x32_f16(aF0, b03, acc3, 0, 0, 0);
    acc4 = __builtin_amdgcn_mfma_f32_16x16x32_f16(aF0, b04, acc4, 0, 0, 0);
    acc0 = __builtin_amdgcn_mfma_f32_16x16x32_f16(aF1, b10, acc0, 0, 0, 0);
    acc1 = __builtin_amdgcn_mfma_f32_16x16x32_f16(aF1, b11, acc1, 0, 0, 0);
    acc2 = __builtin_amdgcn_mfma_f32_16x16x32_f16(aF1, b12, acc2, 0, 0, 0);
    acc3 = __builtin_amdgcn_mfma_f32_16x16x32_f16(aF1, b13, acc3, 0, 0, 0);
    acc4 = __builtin_amdgcn_mfma_f32_16x16x32_f16(aF1, b14, acc4, 0, 0, 0);
  }

  float* prow = part + (((size_t)z * Bz + b) * Nn + i0) * 80;
  #pragma unroll
  for (int r = 0; r < 4; ++r) {
    int ir = quad * 4 + r;
    prow[(size_t)ir * 80 + 0  + ln15] = acc0[r];
    prow[(size_t)ir * 80 + 16 + ln15] = acc1[r];
    prow[(size_t)ir * 80 + 32 + ln15] = acc2[r];
    prow[(size_t)ir * 80 + 48 + ln15] = acc3[r];
    prow[(size_t)ir * 80 + 64 + ln15] = acc4[r];  // col 64 = denominator; 65..79 junk
  }
}

// ---- finalize: out[row][l] = (sum_z num) / (sum_z den) / n
__global__ __launch_bounds__(256) void k_fin(const float* __restrict__ part,
                                             float* __restrict__ out) {
  const int t = threadIdx.x;
  const int rl = t >> 6, l = t & 63;
  const size_t row = (size_t)blockIdx.x * 4 + rl;   // row in [0, Bz*Nn)
  float num = 0.f, den = 0.f;
  #pragma unroll
  for (int z = 0; z < KSPLIT; ++z) {
    const float* p = part + ((size_t)z * Bz * Nn + row) * 80;
    num += p[l];
    den += p[64];
  }
  out[row * OUTd + l] = num / den * (1.0f / (float)Nn);
}

extern "C" void kernel_launch(void* const* d_in, const int* in_sizes, int n_in,
                              void* d_out, int out_size, void* d_ws, size_t ws_size,
                              hipStream_t stream) {
  const float* feat   = (const float*)d_in[0];
  const float* adj    = (const float*)d_in[1];
  const float* W_fc   = (const float*)d_in[2];
  const float* b_fc   = (const float*)d_in[3];
  const float* W_attn = (const float*)d_in[4];
  (void)d_in[5]; // b_attn cancels in softmax
  float* out = (float*)d_out;

  char* ws = (char*)d_ws;
  _Float16* Gt = (_Float16*)ws;                               // 4*80*4096*2 = 2,621,440 B
  _Float16* Ut = (_Float16*)(ws + 2621440);                   // 80*256*2   =    40,960 B
  float*    w_s = (float*)(ws + 2621440 + 40960);             // 1024 B
  float*    hb  = (float*)(ws + 2621440 + 40960 + 1024);      // 256 B
  float*    sb  = (float*)(ws + 2621440 + 40960 + 1024 + 256);// 4 B
  float*    part = (float*)(ws + 2664448);                    // 4*4*4096*80*4 = 20,971,520 B

  k_prep_ws<<<1, 256, 0, stream>>>(W_attn, b_fc, w_s, hb, sb);
  k_prep_ut<<<65, 256, 0, stream>>>(W_fc, w_s, Ut);
  k_feat<<<dim3(64, 4), 256, 0, stream>>>(feat, Ut, hb, sb, Gt);
  k_agg<<<dim3(64, 4, KSPLIT), 256, 0, stream>>>(adj, Gt, part);
  k_fin<<<Bz * Nn / 4, 256, 0, stream>>>(part, out);
}

// Round 4
// 411.840 us; speedup vs baseline: 1.0340x; 1.0340x over previous
//
#include <hip/hip_runtime.h>
#include <stdint.h>
#include <math.h>

// GAT layer, restructured:
//   dst-term and b_attn cancel in softmax over j; masked exp()==0 exactly.
//   p_j = exp(src_j) (no max needed: |src|<~0.7), G = [p*hsum | p] in fp16,
//   out = (adj @ G_num) / (adj @ p) / n via f16 MFMA, adj converted on the fly.
// R4: revert split-K (R3 showed it neutral->negative: k_agg already ~BW-bound);
//     merge prep kernels (3 launches total).

#define Bz   4
#define Nn   4096
#define Dd   256
#define OUTd 64
#define GTR  80   // 64 hsum rows + 1 p row + 15 pad rows (poison; cols 65..79 ignored)

typedef float    f32x4   __attribute__((ext_vector_type(4)));
typedef __fp16   fp16x2  __attribute__((ext_vector_type(2)));   // cvt_pkrtz return type
typedef _Float16 half8_t __attribute__((ext_vector_type(8)));

__device__ inline half8_t cvt8(float4 a, float4 b) {
  union { fp16x2 h2[4]; half8_t h8; } r;
  r.h2[0] = __builtin_amdgcn_cvt_pkrtz(a.x, a.y);
  r.h2[1] = __builtin_amdgcn_cvt_pkrtz(a.z, a.w);
  r.h2[2] = __builtin_amdgcn_cvt_pkrtz(b.x, b.y);
  r.h2[3] = __builtin_amdgcn_cvt_pkrtz(b.z, b.w);
  return r.h8;
}

// ---- prep (merged): Ut rows 0..63 (head-summed W_fc), Ut row 64 (src vector),
//      hb[l] = sum_h b_fc, sb = b_fc . w_s.  w_s recomputed in blocks 64/65.
__global__ __launch_bounds__(256) void k_prep(const float* __restrict__ W_fc,
                                              const float* __restrict__ W_attn,
                                              const float* __restrict__ b_fc,
                                              _Float16* __restrict__ Ut,
                                              float* __restrict__ hb,
                                              float* __restrict__ sb) {
  const int bx = blockIdx.x, t = threadIdx.x;
  if (bx < 64) {
    const int l = bx, d = t;
    float v = W_fc[l * 256 + d] + W_fc[(64 + l) * 256 + d] +
              W_fc[(128 + l) * 256 + d] + W_fc[(192 + l) * 256 + d];
    Ut[l * 256 + d] = (_Float16)v;
    return;
  }
  __shared__ float ws_sh[256];   // w_s[ho], ho = h*64+o
  {
    const int h = t >> 6, o = t & 63;
    float s = 0.f;
    for (int k = 0; k < 4; ++k) s += W_attn[k * 512 + h * 128 + o];
    ws_sh[t] = s * 0.25f;
  }
  __syncthreads();
  if (bx == 64) {
    const int d = t;
    float v = 0.f;
    for (int ho = 0; ho < 256; ++ho) v += W_fc[ho * 256 + d] * ws_sh[ho];
    Ut[64 * 256 + d] = (_Float16)v;
  } else {
    __shared__ float red[256];
    red[t] = b_fc[t] * ws_sh[t];
    if (t < 64) hb[t] = b_fc[t] + b_fc[64 + t] + b_fc[128 + t] + b_fc[192 + t];
    __syncthreads();
    if (t == 0) {
      float a = 0.f;
      for (int i = 0; i < 256; ++i) a += red[i];
      *sb = a;
    }
  }
}

// ---- stage 1: Gt[b][l][j] = fp16(p_j * hsum_lj), Gt[b][64][j] = fp16(p_j)
__global__ __launch_bounds__(256) void k_feat(const float* __restrict__ feat,
                                              const _Float16* __restrict__ Ut,
                                              const float* __restrict__ hb,
                                              const float* __restrict__ sb,
                                              _Float16* __restrict__ Gt) {
  const int b = blockIdx.y;
  const int tid = threadIdx.x;
  const int lane = tid & 63;
  const int wv = tid >> 6;
  const int ln15 = lane & 15;
  const int quad = lane >> 4;
  const int j = blockIdx.x * 64 + wv * 16 + ln15;

  const float* frow = feat + ((size_t)b * Nn + j) * Dd + quad * 8;
  f32x4 acc0 = {0,0,0,0}, acc1 = {0,0,0,0}, acc2 = {0,0,0,0}, acc3 = {0,0,0,0}, acc4 = {0,0,0,0};

  #pragma unroll
  for (int d0 = 0; d0 < Dd; d0 += 32) {
    float4 F0 = *(const float4*)(frow + d0);
    float4 F1 = *(const float4*)(frow + d0 + 4);
    half8_t bf = cvt8(F0, F1);
    const _Float16* up = Ut + (size_t)ln15 * Dd + d0 + quad * 8;
    acc0 = __builtin_amdgcn_mfma_f32_16x16x32_f16(*(const half8_t*)(up + 0 * 16 * Dd), bf, acc0, 0, 0, 0);
    acc1 = __builtin_amdgcn_mfma_f32_16x16x32_f16(*(const half8_t*)(up + 1 * 16 * Dd), bf, acc1, 0, 0, 0);
    acc2 = __builtin_amdgcn_mfma_f32_16x16x32_f16(*(const half8_t*)(up + 2 * 16 * Dd), bf, acc2, 0, 0, 0);
    acc3 = __builtin_amdgcn_mfma_f32_16x16x32_f16(*(const half8_t*)(up + 3 * 16 * Dd), bf, acc3, 0, 0, 0);
    acc4 = __builtin_amdgcn_mfma_f32_16x16x32_f16(*(const half8_t*)(up + 4 * 16 * Dd), bf, acc4, 0, 0, 0);
  }
  float srcv = __shfl(acc4[0], ln15) + sb[0];
  float p = expf(srcv);
  _Float16* gb = Gt + (size_t)b * GTR * Nn;
  #pragma unroll
  for (int r = 0; r < 4; ++r) {
    int lb = quad * 4 + r;
    gb[(size_t)(0  + lb) * Nn + j] = (_Float16)((acc0[r] + hb[0  + lb]) * p);
    gb[(size_t)(16 + lb) * Nn + j] = (_Float16)((acc1[r] + hb[16 + lb]) * p);
    gb[(size_t)(32 + lb) * Nn + j] = (_Float16)((acc2[r] + hb[32 + lb]) * p);
    gb[(size_t)(48 + lb) * Nn + j] = (_Float16)((acc3[r] + hb[48 + lb]) * p);
  }
  if (quad == 0) gb[(size_t)64 * Nn + j] = (_Float16)p;
}

// ---- stage 2: out[b][i][l] = (adj[b] @ Gt^T)[i][l] / (adj[b] @ p)[i] / n
// Per wave: 16 rows (i) x 80 cols; A = adj tile loaded global->reg in frag layout, cvt to fp16.
__global__ __launch_bounds__(256) void k_agg(const float* __restrict__ adj,
                                             const _Float16* __restrict__ Gt,
                                             float* __restrict__ out) {
  const int b = blockIdx.y;
  const int tid = threadIdx.x;
  const int lane = tid & 63;
  const int wv = tid >> 6;
  const int ln15 = lane & 15;
  const int quad = lane >> 4;
  const int i0 = blockIdx.x * 64 + wv * 16;

  const float* arow = adj + ((size_t)b * Nn + (i0 + ln15)) * (size_t)Nn + quad * 8;
  const _Float16* g0 = Gt + ((size_t)b * GTR + ln15) * Nn + quad * 8;
  const _Float16* g1 = g0 + (size_t)16 * Nn;
  const _Float16* g2 = g0 + (size_t)32 * Nn;
  const _Float16* g3 = g0 + (size_t)48 * Nn;
  const _Float16* g4 = g0 + (size_t)64 * Nn;

  f32x4 acc0 = {0,0,0,0}, acc1 = {0,0,0,0}, acc2 = {0,0,0,0}, acc3 = {0,0,0,0}, acc4 = {0,0,0,0};

  for (int k0 = 0; k0 < Nn; k0 += 64) {
    float4 A0 = *(const float4*)(arow + k0);
    float4 A1 = *(const float4*)(arow + k0 + 4);
    float4 A2 = *(const float4*)(arow + k0 + 32);
    float4 A3 = *(const float4*)(arow + k0 + 36);
    half8_t b00 = *(const half8_t*)(g0 + k0);
    half8_t b01 = *(const half8_t*)(g1 + k0);
    half8_t b02 = *(const half8_t*)(g2 + k0);
    half8_t b03 = *(const half8_t*)(g3 + k0);
    half8_t b04 = *(const half8_t*)(g4 + k0);
    half8_t b10 = *(const half8_t*)(g0 + k0 + 32);
    half8_t b11 = *(const half8_t*)(g1 + k0 + 32);
    half8_t b12 = *(const half8_t*)(g2 + k0 + 32);
    half8_t b13 = *(const half8_t*)(g3 + k0 + 32);
    half8_t b14 = *(const half8_t*)(g4 + k0 + 32);
    half8_t aF0 = cvt8(A0, A1);   // adj is exactly 0/1 -> exact in fp16
    half8_t aF1 = cvt8(A2, A3);
    acc0 = __builtin_amdgcn_mfma_f32_16x16x32_f16(aF0, b00, acc0, 0, 0, 0);
    acc1 = __builtin_amdgcn_mfma_f32_16x16x32_f16(aF0, b01, acc1, 0, 0, 0);
    acc2 = __builtin_amdgcn_mfma_f32_16x16x32_f16(aF0, b02, acc2, 0, 0, 0);
    acc3 = __builtin_amdgcn_mfma_f32_16x16x32_f16(aF0, b03, acc3, 0, 0, 0);
    acc4 = __builtin_amdgcn_mfma_f32_16x16x32_f16(aF0, b04, acc4, 0, 0, 0);
    acc0 = __builtin_amdgcn_mfma_f32_16x16x32_f16(aF1, b10, acc0, 0, 0, 0);
    acc1 = __builtin_amdgcn_mfma_f32_16x16x32_f16(aF1, b11, acc1, 0, 0, 0);
    acc2 = __builtin_amdgcn_mfma_f32_16x16x32_f16(aF1, b12, acc2, 0, 0, 0);
    acc3 = __builtin_amdgcn_mfma_f32_16x16x32_f16(aF1, b13, acc3, 0, 0, 0);
    acc4 = __builtin_amdgcn_mfma_f32_16x16x32_f16(aF1, b14, acc4, 0, 0, 0);
  }

  // denominator (col 64 = tile4 local col 0) held by lane (lane & 48); broadcast per row
  float den0 = __shfl(acc4[0], lane & 48);
  float den1 = __shfl(acc4[1], lane & 48);
  float den2 = __shfl(acc4[2], lane & 48);
  float den3 = __shfl(acc4[3], lane & 48);
  const float invn = 1.0f / (float)Nn;
  float* orow = out + ((size_t)b * Nn + i0) * OUTd;
  #pragma unroll
  for (int r = 0; r < 4; ++r) {
    float d = (r == 0) ? den0 : (r == 1) ? den1 : (r == 2) ? den2 : den3;
    float rd = invn / d;
    int ir = quad * 4 + r;
    orow[(size_t)ir * OUTd + 0  + ln15] = acc0[r] * rd;
    orow[(size_t)ir * OUTd + 16 + ln15] = acc1[r] * rd;
    orow[(size_t)ir * OUTd + 32 + ln15] = acc2[r] * rd;
    orow[(size_t)ir * OUTd + 48 + ln15] = acc3[r] * rd;
  }
}

extern "C" void kernel_launch(void* const* d_in, const int* in_sizes, int n_in,
                              void* d_out, int out_size, void* d_ws, size_t ws_size,
                              hipStream_t stream) {
  const float* feat   = (const float*)d_in[0];
  const float* adj    = (const float*)d_in[1];
  const float* W_fc   = (const float*)d_in[2];
  const float* b_fc   = (const float*)d_in[3];
  const float* W_attn = (const float*)d_in[4];
  (void)d_in[5]; // b_attn cancels in softmax
  float* out = (float*)d_out;

  char* ws = (char*)d_ws;
  _Float16* Gt = (_Float16*)ws;                               // 4*80*4096*2 = 2,621,440 B
  _Float16* Ut = (_Float16*)(ws + 2621440);                   // 80*256*2   =    40,960 B
  float*    hb  = (float*)(ws + 2621440 + 40960);             // 256 B
  float*    sb  = (float*)(ws + 2621440 + 40960 + 256);       // 4 B

  k_prep<<<66, 256, 0, stream>>>(W_fc, W_attn, b_fc, Ut, hb, sb);
  k_feat<<<dim3(64, 4), 256, 0, stream>>>(feat, Ut, hb, sb, Gt);
  k_agg<<<dim3(64, 4), 256, 0, stream>>>(adj, Gt, out);
}